// Round 20
// baseline (446.768 us; speedup 1.0000x reference)
//
#include <hip/hip_runtime.h>
#include <math.h>

#define BB 8
#define HH 512
#define WW 1024
#define HW (HH * WW)          // 524288 = 2^19
#define NPIX (BB * HW)        // 4194304
#define NSEG 16               // segments 1..16 (0 skipped)
#define SUPPRESS 0.1f

// ws layout (bytes):
//   moments4 : double[4][8][16][14] @ 0      (57344)   4-way spread partials
//   res4     : double[4][8][16]     @ 57344  (4096)
//   scal64   : double[64][4]        @ 61440  (2048)    [dx,dy,Sb,Sbf] partials
//   maxfg64  : unsigned[64]         @ 63488  (256)
//   params   : float[128*6]         @ 63744  (3072)
//   valid    : int[128]             @ 66816  (512)
//   ctrU,ctrP: unsigned             @ 67328, 67332     last-block tickets

__device__ __forceinline__ float wave_sum(float t) {
    #pragma unroll
    for (int off = 32; off > 0; off >>= 1) t += __shfl_down(t, off);
    return t;
}

#define REP8(M) M(0) M(1) M(2) M(3) M(4) M(5) M(6) M(7)

// ---------------- bodies (r17-validated verbatim) ----------------
__device__ void moments_body(
    const float* __restrict__ flow, const int* __restrict__ masks,
    double* __restrict__ moments4, float* bins, int bid)
{
    const int tid  = threadIdx.x;
    const int lane = tid & 63;
    const int wid  = tid >> 6;
    const int colg = bid & 15;
    const int rowg = (bid >> 4) & 7;
    const int b    = bid >> 7;
    const int par  = bid & 3;

    const int c0 = colg * 64;
    const int r0 = rowg * 64;

    const float* fu = flow + (long long)b * (2LL * HW);
    const float* fv = fu + HW;
    const int*   mk = masks + (long long)b * HW;
    const int*   mrow = mk + r0 * WW + c0 + lane;
    const float* urow = fu + r0 * WW + c0 + lane;
    const float* vrow = fv + r0 * WW + c0 + lane;

    for (int i = tid; i < 2496; i += 256)
        *(float4*)&bins[i * 4] = make_float4(0.f, 0.f, 0.f, 0.f);
    __syncthreads();

    int   m0 = mrow[0];
    float u0 = urow[0], v0 = vrow[0];
    int   m1 = mrow[WW];
    float u1 = urow[WW], v1 = vrow[WW];

#define MPROC(RR, MM, UU, VV) { \
    const float y = (float)(r0 + (RR)); \
    float* bp = &bins[(MM) * 576 + lane]; \
    if (wid == 0) { \
        float b0 = bp[0], b1 = bp[64], b2 = bp[128]; \
        b0 += 1.f; b1 += y; b2 = fmaf(y, y, b2); \
        bp[0] = b0; bp[64] = b1; bp[128] = b2; \
    } else if (wid == 1) { \
        float b3 = bp[192], b5 = bp[320]; \
        b3 += (UU); b5 = fmaf((UU), (UU), b5); \
        bp[192] = b3; bp[320] = b5; \
    } else if (wid == 2) { \
        float b4 = bp[256], b6 = bp[384]; \
        b4 += (VV); b6 = fmaf((VV), (VV), b6); \
        bp[256] = b4; bp[384] = b6; \
    } else { \
        float b7 = bp[448], b8 = bp[512]; \
        b7 = fmaf(y, (UU), b7); b8 = fmaf(y, (VV), b8); \
        bp[448] = b7; bp[512] = b8; \
    } }

    #pragma unroll 1
    for (int r = 0; r < 64; r += 2) {
        const int o2 = ((r + 2) & 63) * WW;
        const int o3 = ((r + 3) & 63) * WW;
        const int   m2 = mrow[o2];
        const float u2 = urow[o2], v2 = vrow[o2];
        const int   m3 = mrow[o3];
        const float u3 = urow[o3], v3 = vrow[o3];

        MPROC(r, m0, u0, v0)
        MPROC(r + 1, m1, u1, v1)

        m0 = m2; u0 = u2; v0 = v2;
        m1 = m3; u1 = u3; v1 = v3;
    }
    __syncthreads();

    const unsigned long long SRC = 0x84736543210100ULL;
    const unsigned long long PW  = 0x01010000012010ULL;
    double* cell = moments4 + par * 1792 + b * 224;
    {
        const int p   = tid;
        const int act = (p < 224);
        const int pc  = act ? p : 0;
        const int segm = pc / 14;
        const int feat = pc - segm * 14;
        const int srcb = (int)((SRC >> (4 * feat)) & 15);
        const int pw   = (int)((PW  >> (4 * feat)) & 15);
        const float* bp = &bins[(segm + 1) * 576 + srcb * 64];
        float acc = 0.f;
        #pragma unroll 8
        for (int l0 = 0; l0 < 64; ++l0) {
            const int l = (l0 + lane) & 63;
            const float xv = (float)(c0 + l);
            const float w = (pw == 0) ? 1.f : ((pw == 1) ? xv : xv * xv);
            acc = fmaf(bp[l], w, acc);
        }
        if (act) atomicAdd(&cell[segm * 14 + feat], (double)acc);
    }
}

__device__ void stencil_body(
    const float* __restrict__ flow, const int* __restrict__ masks,
    const float* __restrict__ images,
    double* __restrict__ scal64, unsigned* __restrict__ maxfg64,
    char* smem, int bid)
{
    float    (*smX)[260] = (float (*)[260])(smem);
    float    (*smW)[260] = (float (*)[260])(smem + 4160);
    unsigned (*mX)[260]  = (unsigned (*)[260])(smem + 8320);
    unsigned (*mW)[260]  = (unsigned (*)[260])(smem + 12480);
    float    (*gX)[260]  = (float (*)[260])(smem + 16640);
    float    (*ue)[260]  = (float (*)[260])(smem + 18720);
    float    (*ve)[260]  = (float (*)[260])(smem + 20800);
    float    (*wred)[5]  = (float (*)[5])(smem + 22880);

    const int tid = threadIdx.x;
    const int lane = tid & 63;
    const long long base = (long long)bid * 2048;
    const int b  = (int)(base >> 19);
    const int h0 = (int)((base & (HW - 1)) >> 10);

    const float* fu = flow + (long long)b * (2LL * HW);
    const float* fv = fu + HW;
    const int*   mk = masks + (long long)b * HW;
    const float* i0 = images + (long long)b * (3LL * HW);
    const float* i1 = i0 + HW;
    const float* i2 = i1 + HW;

    const int c4 = tid * 4;
    float4 m4a[4];
    unsigned mbp[4];
    float4 ur[3], vr[3];
    float4 gr[3];

    #pragma unroll
    for (int r = 0; r < 4; ++r) {
        const int grow = h0 - 1 + r;
        const int mr = grow < 0 ? 0 : (grow > HH - 1 ? HH - 1 : grow);
        const int4 mv = *(const int4*)&mk[mr * WW + c4];
        mbp[r] = (unsigned)(mv.x & 255) | ((unsigned)(mv.y & 255) << 8) |
                 ((unsigned)(mv.z & 255) << 16) | ((unsigned)(mv.w & 255) << 24);

        float4 u4 = make_float4(0.f, 0.f, 0.f, 0.f);
        float4 v4 = make_float4(0.f, 0.f, 0.f, 0.f);
        if (grow >= 0 && grow <= HH - 1) {
            u4 = *(const float4*)&fu[grow * WW + c4];
            v4 = *(const float4*)&fv[grow * WW + c4];
        }
        float4 m4;
        m4.x = sqrtf(u4.x * u4.x + v4.x * v4.x);
        m4.y = sqrtf(u4.y * u4.y + v4.y * v4.y);
        m4.z = sqrtf(u4.z * u4.z + v4.z * v4.z);
        m4.w = sqrtf(u4.w * u4.w + v4.w * v4.w);
        m4a[r] = m4;
        smX[r][tid] = m4.x;
        smW[r][tid + 1] = m4.w;
        mX[r][tid] = (unsigned)(mv.x & 255);
        mW[r][tid + 1] = (unsigned)(mv.w & 255);
        if (tid == 0)   { smW[r][0] = 0.f;   mW[r][0] = (unsigned)(mv.x & 255); }
        if (tid == 255) { smX[r][256] = 0.f; mX[r][256] = (unsigned)(mv.w & 255); }
        if (r >= 1) { ur[r - 1] = u4; vr[r - 1] = v4; }
    }
    #pragma unroll
    for (int r = 0; r < 3; ++r) {
        const int grow = h0 + r;
        float4 g4 = make_float4(0.f, 0.f, 0.f, 0.f);
        if (grow <= HH - 1) {
            const float4 a  = *(const float4*)&i0[grow * WW + c4];
            const float4 bq = *(const float4*)&i1[grow * WW + c4];
            const float4 c  = *(const float4*)&i2[grow * WW + c4];
            g4.x = (a.x + bq.x + c.x) * (1.f / 3.f);
            g4.y = (a.y + bq.y + c.y) * (1.f / 3.f);
            g4.z = (a.z + bq.z + c.z) * (1.f / 3.f);
            g4.w = (a.w + bq.w + c.w) * (1.f / 3.f);
        }
        gr[r] = g4;
        if (r < 2) gX[r][tid] = g4.x;
    }
    ue[0][tid] = ur[0].x; ve[0][tid] = vr[0].x;
    ue[1][tid] = ur[1].x; ve[1][tid] = vr[1].x;
    __syncthreads();

    float a_dx = 0.f, a_dy = 0.f, a_sb = 0.f, a_sbf = 0.f, mfg = 0.f;

    #pragma unroll
    for (int lr = 0; lr < 2; ++lr) {
        const int h = h0 + lr;
        float a[3][6];
        unsigned long long kw[3];
        #pragma unroll
        for (int r = 0; r < 3; ++r) {
            const int rr = lr + r;
            const float4 own = m4a[rr];
            a[r][0] = smW[rr][tid];
            a[r][1] = own.x; a[r][2] = own.y; a[r][3] = own.z; a[r][4] = own.w;
            a[r][5] = smX[rr][tid + 1];
            kw[r] = (unsigned long long)mW[rr][tid]
                  | ((unsigned long long)mbp[rr] << 8)
                  | ((unsigned long long)mX[rr][tid + 1] << 40);
        }
        const float4 gc = gr[lr];
        const float4 gd4 = gr[lr + 1];
        const float gval[5] = {gc.x, gc.y, gc.z, gc.w, gX[lr][tid + 1]};
        const float gd[4]  = {gd4.x, gd4.y, gd4.z, gd4.w};
        const float4 uc4 = ur[lr],  vc4 = vr[lr];
        const float4 ud4 = ur[lr + 1], vd4 = vr[lr + 1];
        const float uc[5] = {uc4.x, uc4.y, uc4.z, uc4.w, ue[lr][tid + 1]};
        const float vc[5] = {vc4.x, vc4.y, vc4.z, vc4.w, ve[lr][tid + 1]};
        const float ud[4] = {ud4.x, ud4.y, ud4.z, ud4.w};
        const float vd[4] = {vd4.x, vd4.y, vd4.z, vd4.w};

        #pragma unroll
        for (int j = 0; j < 4; ++j) {
            const int w = c4 + j;
            const unsigned cseg = (unsigned)((kw[1] >> (8 * (j + 1))) & 255);
            int bnd = (((kw[0] >> (8 * j)) & 255) != cseg)
                    | (((kw[0] >> (8 * (j + 1))) & 255) != cseg)
                    | (((kw[0] >> (8 * (j + 2))) & 255) != cseg)
                    | (((kw[1] >> (8 * j)) & 255) != cseg)
                    | (((kw[1] >> (8 * (j + 2))) & 255) != cseg)
                    | (((kw[2] >> (8 * j)) & 255) != cseg)
                    | (((kw[2] >> (8 * (j + 1))) & 255) != cseg)
                    | (((kw[2] >> (8 * (j + 2))) & 255) != cseg);

            const float fgx = (a[0][j + 2] - a[0][j]) + 2.f * (a[1][j + 2] - a[1][j]) +
                              (a[2][j + 2] - a[2][j]);
            const float fgy = (a[2][j] + 2.f * a[2][j + 1] + a[2][j + 2]) -
                              (a[0][j] + 2.f * a[0][j + 1] + a[0][j + 2]);
            const float fgraw = fabsf(fgx) + fabsf(fgy);
            mfg = fmaxf(mfg, fgraw);
            if (bnd) { a_sb += 1.f; a_sbf += fgraw; }

            const float u = uc[j], v = vc[j], g0 = gval[j];
            if (w < WW - 1) {
                const float wgt = expf(-fabsf(gval[j + 1] - g0) * 10.f) * (bnd ? SUPPRESS : 1.f);
                a_dx += (fabsf(uc[j + 1] - u) + fabsf(vc[j + 1] - v)) * wgt;
            }
            if (h < HH - 1) {
                const float wgt = expf(-fabsf(gd[j] - g0) * 10.f) * (bnd ? SUPPRESS : 1.f);
                a_dy += (fabsf(ud[j] - u) + fabsf(vd[j] - v)) * wgt;
            }
        }
    }

    for (int off = 32; off > 0; off >>= 1) {
        a_dx += __shfl_down(a_dx, off);
        a_dy += __shfl_down(a_dy, off);
        a_sb += __shfl_down(a_sb, off);
        a_sbf += __shfl_down(a_sbf, off);
        mfg = fmaxf(mfg, __shfl_down(mfg, off));
    }
    if (lane == 0) {
        const int wv = tid >> 6;
        wred[wv][0] = a_dx; wred[wv][1] = a_dy; wred[wv][2] = a_sb;
        wred[wv][3] = a_sbf; wred[wv][4] = mfg;
    }
    __syncthreads();
    if (tid == 0) {
        float dx = 0.f, dy = 0.f, sb = 0.f, sbf = 0.f, mf = 0.f;
        for (int i = 0; i < 4; ++i) {
            dx += wred[i][0]; dy += wred[i][1]; sb += wred[i][2];
            sbf += wred[i][3]; mf = fmaxf(mf, wred[i][4]);
        }
        const int sl = bid & 63;
        atomicAdd(&scal64[sl * 4 + 0], (double)dx);
        atomicAdd(&scal64[sl * 4 + 1], (double)dy);
        atomicAdd(&scal64[sl * 4 + 2], (double)sb);
        atomicAdd(&scal64[sl * 4 + 3], (double)sbf);
        atomicMax(&maxfg64[sl], __float_as_uint(mf));
    }
}

// solve body: runs in the LAST uber block (256 threads; i<128 active).
// svar/scnt carved from smem union (no extra LDS).
__device__ void solve_body(
    const double* __restrict__ moments4,
    float* __restrict__ params, int* __restrict__ valid,
    float* __restrict__ out, char* smem)
{
    double* svar = (double*)smem;            // 128 * 8 = 1024 B
    int*    scnt = (int*)(smem + 1024);      // 128 * 4 = 512 B
    const int i = threadIdx.x;
    if (i < 128) {
        double m[14];
        #pragma unroll
        for (int k = 0; k < 14; ++k) {
            double s = 0.0;
            #pragma unroll
            for (int par = 0; par < 4; ++par) s += moments4[par * 1792 + i * 14 + k];
            m[k] = s;
        }
        const double n = m[0];
        const int vh = (n >= 100.0) ? 1 : 0;
        float p[6] = {0.f, 0.f, 0.f, 0.f, 0.f, 0.f};
        if (vh) {
            double A[3][3] = {{m[3], m[4], m[1]},
                              {m[4], m[5], m[2]},
                              {m[1], m[2], n}};
            double Bm[3][2] = {{m[10], m[12]},
                               {m[11], m[13]},
                               {m[6],  m[7]}};
            for (int k = 0; k < 3; ++k) {
                int piv = k; double mx = fabs(A[k][k]);
                for (int r = k + 1; r < 3; ++r) {
                    double a = fabs(A[r][k]);
                    if (a > mx) { mx = a; piv = r; }
                }
                if (piv != k) {
                    for (int c = 0; c < 3; ++c) { double t = A[k][c]; A[k][c] = A[piv][c]; A[piv][c] = t; }
                    for (int c = 0; c < 2; ++c) { double t = Bm[k][c]; Bm[k][c] = Bm[piv][c]; Bm[piv][c] = t; }
                }
                const double inv = 1.0 / A[k][k];
                for (int r = k + 1; r < 3; ++r) {
                    const double f = A[r][k] * inv;
                    for (int c = k; c < 3; ++c) A[r][c] -= f * A[k][c];
                    Bm[r][0] -= f * Bm[k][0];
                    Bm[r][1] -= f * Bm[k][1];
                }
            }
            double X[3][2];
            for (int c = 0; c < 2; ++c) {
                X[2][c] = Bm[2][c] / A[2][2];
                X[1][c] = (Bm[1][c] - A[1][2] * X[2][c]) / A[1][1];
                X[0][c] = (Bm[0][c] - A[0][1] * X[1][c] - A[0][2] * X[2][c]) / A[0][0];
            }
            p[0] = (float)X[0][0]; p[1] = (float)X[1][0]; p[2] = (float)X[2][0];
            p[3] = (float)X[0][1]; p[4] = (float)X[1][1]; p[5] = (float)X[2][1];
        }
        valid[i] = vh;
        for (int c = 0; c < 6; ++c) params[i * 6 + c] = p[c];

        const int vv = (n >= 50.0) ? 1 : 0;
        double var = 0.0;
        if (vv) {
            const double ns = (n > 2.0) ? n : 2.0;
            const double var_u = (m[8] - m[6] * m[6] / ns) / (ns - 1.0);
            const double var_v = (m[9] - m[7] * m[7] / ns) / (ns - 1.0);
            var = var_u + var_v;
        }
        svar[i] = var; scnt[i] = vv;
    }
    __syncthreads();
    for (int s = 64; s > 0; s >>= 1) {
        if (i < s) { svar[i] += svar[i + s]; scnt[i] += scnt[i + s]; }
        __syncthreads();
    }
    if (i == 0) out[2] = (float)(svar[0] / (double)(scnt[0] > 1 ? scnt[0] : 1));
}

__global__ __launch_bounds__(256) void uber_kernel(
    const float* __restrict__ flow,
    const int*   __restrict__ masks,
    const float* __restrict__ images,
    double* __restrict__ moments4,
    double* __restrict__ scal64,
    unsigned* __restrict__ maxfg64,
    float* __restrict__ params,
    int* __restrict__ valid,
    float* __restrict__ out,
    unsigned* __restrict__ ctr)
{
    __shared__ char smem[39936];      // union: moments bins | stencil arrays | solve svar/scnt
    __shared__ unsigned done;
    const int bid = blockIdx.x;       // 3072 = 2048 stencil + 1024 moments, interleaved
    if ((bid % 3) == 2) {
        moments_body(flow, masks, moments4, (float*)smem, bid / 3);
    } else {
        stencil_body(flow, masks, images, scal64, maxfg64, smem,
                     (bid / 3) * 2 + (bid % 3));
    }
    // last-block solve (device-scope atomic ticket; G12/G16-safe)
    __threadfence();
    __syncthreads();
    if (threadIdx.x == 0) done = atomicAdd(ctr, 1u);
    __syncthreads();
    if (done == 3071u) {
        __threadfence();
        solve_body(moments4, params, valid, out, smem);
    }
}

// ---------------- final body: runs in LAST pass2 block ----------------
__device__ void final_body(
    const double* __restrict__ moments4,
    const double* __restrict__ res4,
    const int*    __restrict__ valid,
    const double* __restrict__ scal64,
    const unsigned* __restrict__ maxfg64,
    float* __restrict__ out,
    double* sr, int* sc)
{
    const int i = threadIdx.x;
    if (i < 128) {
        double n = 0.0, rs = 0.0;
        #pragma unroll
        for (int par = 0; par < 4; ++par) {
            n  += moments4[par * 1792 + i * 14];
            rs += res4[par * 128 + i];
        }
        const int vh = valid[i];
        sr[i] = vh ? rs / (n > 1.0 ? n : 1.0) : 0.0;
        sc[i] = vh;
    }
    __syncthreads();
    for (int s = 64; s > 0; s >>= 1) {
        if (i < s) { sr[i] += sr[i + s]; sc[i] += sc[i + s]; }
        __syncthreads();
    }
    if (i == 0) {
        out[0] = (float)(sr[0] / (double)(sc[0] > 1 ? sc[0] : 1));
        double dx = 0.0, dy = 0.0, sb = 0.0, sbf = 0.0;
        float mf = 0.f;
        for (int k = 0; k < 64; ++k) {
            dx += scal64[k * 4 + 0]; dy += scal64[k * 4 + 1];
            sb += scal64[k * 4 + 2]; sbf += scal64[k * 4 + 3];
            mf = fmaxf(mf, __uint_as_float(maxfg64[k]));
        }
        const double maxfg = (double)mf;
        const double maxb = (sb > 0.0) ? 1.0 : 0.0;
        out[1] = (float)((sb - sbf / (maxfg + 1e-6)) / (maxb + 1e-6) / (double)NPIX);
        const double smooth = dx / (double)(2LL * BB * HH * (WW - 1)) +
                              dy / (double)(2LL * BB * (HH - 1) * WW);
        out[3] = (float)smooth;
    }
}

// ---------------- pass 2 + last-block final ----------------
__global__ __launch_bounds__(256) void pass2_kernel(
    const float* __restrict__ flow,
    const int*   __restrict__ masks,
    const float* __restrict__ params,
    double* __restrict__ res4,
    const double* __restrict__ moments4,
    const int*    __restrict__ valid,
    const double* __restrict__ scal64,
    const unsigned* __restrict__ maxfg64,
    float* __restrict__ out,
    unsigned* __restrict__ ctr)
{
    __shared__ float sp[17 * 6];      // row 0 = zeros (background)
    __shared__ double sr[128];
    __shared__ int sc[128];
    __shared__ unsigned done;

    const long long base = (long long)blockIdx.x * 4096;
    const int b      = (int)(base >> 19);
    const int hwbase = (int)(base & (HW - 1));
    const int tid    = threadIdx.x;
    const int lane   = tid & 63;

    if (tid < 6) sp[tid] = 0.f;
    if (tid < 96) sp[6 + tid] = params[b * 96 + tid];
    __syncthreads();

    const float* fu = flow + (long long)b * (2LL * HW);
    const float* fv = fu + HW;
    const int*   mk = masks + (long long)b * HW;

#define DECLR(i) float r_##i = 0.f;
    REP8(DECLR)
#define DECLR2(i) float q_##i = 0.f;
    REP8(DECLR2)

    #pragma unroll
    for (int it = 0; it < 4; ++it) {
        const int i4 = hwbase + it * 1024 + tid * 4;
        const int4   m4 = *(const int4*)&mk[i4];
        const float4 u4 = *(const float4*)&fu[i4];
        const float4 v4 = *(const float4*)&fv[i4];
        const int segs[4] = {m4.x, m4.y, m4.z, m4.w};
        const float us[4] = {u4.x, u4.y, u4.z, u4.w};
        const float vs[4] = {v4.x, v4.y, v4.z, v4.w};
        #pragma unroll
        for (int j = 0; j < 4; ++j) {
            const int seg = segs[j];
            const float* pf = &sp[seg * 6];
            const int hw = i4 + j;
            const float x = (float)(hw & 1023), y = (float)((hw & (HW - 1)) >> 10);
            const float du = us[j] - (x * pf[0] + y * pf[1] + pf[2]);
            const float dv = vs[j] - (x * pf[3] + y * pf[4] + pf[5]);
            const float r = sqrtf(du * du + dv * dv);
            const int sr_ = seg - 1;
#define STEPR(i) r_##i += (sr_ == i) ? r : 0.f;
            REP8(STEPR)
#define STEPR2(i) q_##i += (sr_ == 8 + i) ? r : 0.f;
            REP8(STEPR2)
        }
    }

    const int par = blockIdx.x & 3;
    double* rb = &res4[par * 128 + b * 16];
#define FINR(i) { const float s = wave_sum(r_##i); \
    if (lane == 0) atomicAdd(rb + i, (double)s); }
    REP8(FINR)
#define FINR2(i) { const float s = wave_sum(q_##i); \
    if (lane == 0) atomicAdd(rb + 8 + i, (double)s); }
    REP8(FINR2)

    // last-block final (device-scope atomic ticket)
    __threadfence();
    __syncthreads();
    if (tid == 0) done = atomicAdd(ctr, 1u);
    __syncthreads();
    if (done == (unsigned)(NPIX / 4096 - 1)) {
        __threadfence();
        final_body(moments4, res4, valid, scal64, maxfg64, out, sr, sc);
    }
}

extern "C" void kernel_launch(void* const* d_in, const int* in_sizes, int n_in,
                              void* d_out, int out_size, void* d_ws, size_t ws_size,
                              hipStream_t stream)
{
    const float* flow   = (const float*)d_in[0];
    const int*   masks  = (const int*)d_in[1];
    const float* images = (const float*)d_in[2];
    float* out = (float*)d_out;

    char* ws = (char*)d_ws;
    double*   moments4 = (double*)(ws);             // 0     .. 57344
    double*   res4     = (double*)(ws + 57344);     // 57344 .. 61440
    double*   scal64   = (double*)(ws + 61440);     // 61440 .. 63488
    unsigned* maxfg64  = (unsigned*)(ws + 63488);   // 63488 .. 63744
    float*    params   = (float*)(ws + 63744);      // 63744 .. 66816
    int*      valid    = (int*)(ws + 66816);        // 66816 .. 67328
    unsigned* ctrU     = (unsigned*)(ws + 67328);   // 67328 .. 67332
    unsigned* ctrP     = (unsigned*)(ws + 67332);   // 67332 .. 67336

    hipMemsetAsync(d_ws, 0, 67584, stream);

    uber_kernel<<<dim3(3072), dim3(256), 0, stream>>>(
        flow, masks, images, moments4, scal64, maxfg64, params, valid, out, ctrU);
    pass2_kernel<<<dim3(NPIX / 4096), dim3(256), 0, stream>>>(
        flow, masks, params, res4, moments4, valid, scal64, maxfg64, out, ctrP);
}

// Round 21
// 105.696 us; speedup vs baseline: 4.2269x; 4.2269x over previous
//
#include <hip/hip_runtime.h>
#include <math.h>

#define BB 8
#define HH 512
#define WW 1024
#define HW (HH * WW)          // 524288 = 2^19
#define NPIX (BB * HW)        // 4194304
#define NSEG 16               // segments 1..16 (0 skipped)
#define SUPPRESS 0.1f

// ws layout (bytes):
//   moments4 : double[4][8][16][14] @ 0      (57344)   4-way spread partials
//   res4     : double[4][8][16]     @ 57344  (4096)
//   scal64   : double[64][4]        @ 61440  (2048)    [dx,dy,Sb,Sbf] partials
//   maxfg64  : unsigned[64]         @ 63488  (256)
//   params   : float[128*6]         @ 63744  (3072)
//   valid    : int[128]             @ 66816  (512)

__device__ __forceinline__ float wave_sum(float t) {
    #pragma unroll
    for (int off = 32; off > 0; off >>= 1) t += __shfl_down(t, off);
    return t;
}

#define REP8(M) M(0) M(1) M(2) M(3) M(4) M(5) M(6) M(7)

// ---------------- uber kernel: moments (r15) || stencil (r12), block-specialized ----------------
// Validated r17/r19 optimum (106.5-107.6us total): moments and stencil are
// data-independent and both latency-bound -- run them CONCURRENTLY in one
// dispatch. bid%3==2 -> moments (1024 blocks), else stencil (2048 blocks),
// interleaved for co-residency. LDS = 39KB union (max, not sum).

__device__ void moments_body(
    const float* __restrict__ flow, const int* __restrict__ masks,
    double* __restrict__ moments4, float* bins, int bid)
{
    const int tid  = threadIdx.x;
    const int lane = tid & 63;
    const int wid  = tid >> 6;
    const int colg = bid & 15;
    const int rowg = (bid >> 4) & 7;
    const int b    = bid >> 7;
    const int par  = bid & 3;

    const int c0 = colg * 64;
    const int r0 = rowg * 64;

    const float* fu = flow + (long long)b * (2LL * HW);
    const float* fv = fu + HW;
    const int*   mk = masks + (long long)b * HW;
    const int*   mrow = mk + r0 * WW + c0 + lane;
    const float* urow = fu + r0 * WW + c0 + lane;
    const float* vrow = fv + r0 * WW + c0 + lane;

    for (int i = tid; i < 2496; i += 256)
        *(float4*)&bins[i * 4] = make_float4(0.f, 0.f, 0.f, 0.f);
    __syncthreads();

    int   m0 = mrow[0];
    float u0 = urow[0], v0 = vrow[0];
    int   m1 = mrow[WW];
    float u1 = urow[WW], v1 = vrow[WW];

#define MPROC(RR, MM, UU, VV) { \
    const float y = (float)(r0 + (RR)); \
    float* bp = &bins[(MM) * 576 + lane]; \
    if (wid == 0) { \
        float b0 = bp[0], b1 = bp[64], b2 = bp[128]; \
        b0 += 1.f; b1 += y; b2 = fmaf(y, y, b2); \
        bp[0] = b0; bp[64] = b1; bp[128] = b2; \
    } else if (wid == 1) { \
        float b3 = bp[192], b5 = bp[320]; \
        b3 += (UU); b5 = fmaf((UU), (UU), b5); \
        bp[192] = b3; bp[320] = b5; \
    } else if (wid == 2) { \
        float b4 = bp[256], b6 = bp[384]; \
        b4 += (VV); b6 = fmaf((VV), (VV), b6); \
        bp[256] = b4; bp[384] = b6; \
    } else { \
        float b7 = bp[448], b8 = bp[512]; \
        b7 = fmaf(y, (UU), b7); b8 = fmaf(y, (VV), b8); \
        bp[448] = b7; bp[512] = b8; \
    } }

    #pragma unroll 1
    for (int r = 0; r < 64; r += 2) {
        const int o2 = ((r + 2) & 63) * WW;
        const int o3 = ((r + 3) & 63) * WW;
        const int   m2 = mrow[o2];
        const float u2 = urow[o2], v2 = vrow[o2];
        const int   m3 = mrow[o3];
        const float u3 = urow[o3], v3 = vrow[o3];

        MPROC(r, m0, u0, v0)
        MPROC(r + 1, m1, u1, v1)

        m0 = m2; u0 = u2; v0 = v2;
        m1 = m3; u1 = u3; v1 = v3;
    }
    __syncthreads();

    const unsigned long long SRC = 0x84736543210100ULL;
    const unsigned long long PW  = 0x01010000012010ULL;
    double* cell = moments4 + par * 1792 + b * 224;
    {
        const int p   = tid;
        const int act = (p < 224);
        const int pc  = act ? p : 0;
        const int segm = pc / 14;
        const int feat = pc - segm * 14;
        const int srcb = (int)((SRC >> (4 * feat)) & 15);
        const int pw   = (int)((PW  >> (4 * feat)) & 15);
        const float* bp = &bins[(segm + 1) * 576 + srcb * 64];
        float acc = 0.f;
        #pragma unroll 8
        for (int l0 = 0; l0 < 64; ++l0) {
            const int l = (l0 + lane) & 63;
            const float xv = (float)(c0 + l);
            const float w = (pw == 0) ? 1.f : ((pw == 1) ? xv : xv * xv);
            acc = fmaf(bp[l], w, acc);
        }
        if (act) atomicAdd(&cell[segm * 14 + feat], (double)acc);
    }
}

__device__ void stencil_body(
    const float* __restrict__ flow, const int* __restrict__ masks,
    const float* __restrict__ images,
    double* __restrict__ scal64, unsigned* __restrict__ maxfg64,
    char* smem, int bid)
{
    float    (*smX)[260] = (float (*)[260])(smem);
    float    (*smW)[260] = (float (*)[260])(smem + 4160);
    unsigned (*mX)[260]  = (unsigned (*)[260])(smem + 8320);
    unsigned (*mW)[260]  = (unsigned (*)[260])(smem + 12480);
    float    (*gX)[260]  = (float (*)[260])(smem + 16640);
    float    (*ue)[260]  = (float (*)[260])(smem + 18720);
    float    (*ve)[260]  = (float (*)[260])(smem + 20800);
    float    (*wred)[5]  = (float (*)[5])(smem + 22880);

    const int tid = threadIdx.x;
    const int lane = tid & 63;
    const long long base = (long long)bid * 2048;
    const int b  = (int)(base >> 19);
    const int h0 = (int)((base & (HW - 1)) >> 10);

    const float* fu = flow + (long long)b * (2LL * HW);
    const float* fv = fu + HW;
    const int*   mk = masks + (long long)b * HW;
    const float* i0 = images + (long long)b * (3LL * HW);
    const float* i1 = i0 + HW;
    const float* i2 = i1 + HW;

    const int c4 = tid * 4;
    float4 m4a[4];
    unsigned mbp[4];
    float4 ur[3], vr[3];
    float4 gr[3];

    #pragma unroll
    for (int r = 0; r < 4; ++r) {
        const int grow = h0 - 1 + r;
        const int mr = grow < 0 ? 0 : (grow > HH - 1 ? HH - 1 : grow);
        const int4 mv = *(const int4*)&mk[mr * WW + c4];
        mbp[r] = (unsigned)(mv.x & 255) | ((unsigned)(mv.y & 255) << 8) |
                 ((unsigned)(mv.z & 255) << 16) | ((unsigned)(mv.w & 255) << 24);

        float4 u4 = make_float4(0.f, 0.f, 0.f, 0.f);
        float4 v4 = make_float4(0.f, 0.f, 0.f, 0.f);
        if (grow >= 0 && grow <= HH - 1) {
            u4 = *(const float4*)&fu[grow * WW + c4];
            v4 = *(const float4*)&fv[grow * WW + c4];
        }
        float4 m4;
        m4.x = sqrtf(u4.x * u4.x + v4.x * v4.x);
        m4.y = sqrtf(u4.y * u4.y + v4.y * v4.y);
        m4.z = sqrtf(u4.z * u4.z + v4.z * v4.z);
        m4.w = sqrtf(u4.w * u4.w + v4.w * v4.w);
        m4a[r] = m4;
        smX[r][tid] = m4.x;
        smW[r][tid + 1] = m4.w;
        mX[r][tid] = (unsigned)(mv.x & 255);
        mW[r][tid + 1] = (unsigned)(mv.w & 255);
        if (tid == 0)   { smW[r][0] = 0.f;   mW[r][0] = (unsigned)(mv.x & 255); }
        if (tid == 255) { smX[r][256] = 0.f; mX[r][256] = (unsigned)(mv.w & 255); }
        if (r >= 1) { ur[r - 1] = u4; vr[r - 1] = v4; }
    }
    #pragma unroll
    for (int r = 0; r < 3; ++r) {
        const int grow = h0 + r;
        float4 g4 = make_float4(0.f, 0.f, 0.f, 0.f);
        if (grow <= HH - 1) {
            const float4 a  = *(const float4*)&i0[grow * WW + c4];
            const float4 bq = *(const float4*)&i1[grow * WW + c4];
            const float4 c  = *(const float4*)&i2[grow * WW + c4];
            g4.x = (a.x + bq.x + c.x) * (1.f / 3.f);
            g4.y = (a.y + bq.y + c.y) * (1.f / 3.f);
            g4.z = (a.z + bq.z + c.z) * (1.f / 3.f);
            g4.w = (a.w + bq.w + c.w) * (1.f / 3.f);
        }
        gr[r] = g4;
        if (r < 2) gX[r][tid] = g4.x;
    }
    ue[0][tid] = ur[0].x; ve[0][tid] = vr[0].x;
    ue[1][tid] = ur[1].x; ve[1][tid] = vr[1].x;
    __syncthreads();

    float a_dx = 0.f, a_dy = 0.f, a_sb = 0.f, a_sbf = 0.f, mfg = 0.f;

    #pragma unroll
    for (int lr = 0; lr < 2; ++lr) {
        const int h = h0 + lr;
        float a[3][6];
        unsigned long long kw[3];
        #pragma unroll
        for (int r = 0; r < 3; ++r) {
            const int rr = lr + r;
            const float4 own = m4a[rr];
            a[r][0] = smW[rr][tid];
            a[r][1] = own.x; a[r][2] = own.y; a[r][3] = own.z; a[r][4] = own.w;
            a[r][5] = smX[rr][tid + 1];
            kw[r] = (unsigned long long)mW[rr][tid]
                  | ((unsigned long long)mbp[rr] << 8)
                  | ((unsigned long long)mX[rr][tid + 1] << 40);
        }
        const float4 gc = gr[lr];
        const float4 gd4 = gr[lr + 1];
        const float gval[5] = {gc.x, gc.y, gc.z, gc.w, gX[lr][tid + 1]};
        const float gd[4]  = {gd4.x, gd4.y, gd4.z, gd4.w};
        const float4 uc4 = ur[lr],  vc4 = vr[lr];
        const float4 ud4 = ur[lr + 1], vd4 = vr[lr + 1];
        const float uc[5] = {uc4.x, uc4.y, uc4.z, uc4.w, ue[lr][tid + 1]};
        const float vc[5] = {vc4.x, vc4.y, vc4.z, vc4.w, ve[lr][tid + 1]};
        const float ud[4] = {ud4.x, ud4.y, ud4.z, ud4.w};
        const float vd[4] = {vd4.x, vd4.y, vd4.z, vd4.w};

        #pragma unroll
        for (int j = 0; j < 4; ++j) {
            const int w = c4 + j;
            const unsigned cseg = (unsigned)((kw[1] >> (8 * (j + 1))) & 255);
            int bnd = (((kw[0] >> (8 * j)) & 255) != cseg)
                    | (((kw[0] >> (8 * (j + 1))) & 255) != cseg)
                    | (((kw[0] >> (8 * (j + 2))) & 255) != cseg)
                    | (((kw[1] >> (8 * j)) & 255) != cseg)
                    | (((kw[1] >> (8 * (j + 2))) & 255) != cseg)
                    | (((kw[2] >> (8 * j)) & 255) != cseg)
                    | (((kw[2] >> (8 * (j + 1))) & 255) != cseg)
                    | (((kw[2] >> (8 * (j + 2))) & 255) != cseg);

            const float fgx = (a[0][j + 2] - a[0][j]) + 2.f * (a[1][j + 2] - a[1][j]) +
                              (a[2][j + 2] - a[2][j]);
            const float fgy = (a[2][j] + 2.f * a[2][j + 1] + a[2][j + 2]) -
                              (a[0][j] + 2.f * a[0][j + 1] + a[0][j + 2]);
            const float fgraw = fabsf(fgx) + fabsf(fgy);
            mfg = fmaxf(mfg, fgraw);
            if (bnd) { a_sb += 1.f; a_sbf += fgraw; }

            const float u = uc[j], v = vc[j], g0 = gval[j];
            if (w < WW - 1) {
                const float wgt = expf(-fabsf(gval[j + 1] - g0) * 10.f) * (bnd ? SUPPRESS : 1.f);
                a_dx += (fabsf(uc[j + 1] - u) + fabsf(vc[j + 1] - v)) * wgt;
            }
            if (h < HH - 1) {
                const float wgt = expf(-fabsf(gd[j] - g0) * 10.f) * (bnd ? SUPPRESS : 1.f);
                a_dy += (fabsf(ud[j] - u) + fabsf(vd[j] - v)) * wgt;
            }
        }
    }

    for (int off = 32; off > 0; off >>= 1) {
        a_dx += __shfl_down(a_dx, off);
        a_dy += __shfl_down(a_dy, off);
        a_sb += __shfl_down(a_sb, off);
        a_sbf += __shfl_down(a_sbf, off);
        mfg = fmaxf(mfg, __shfl_down(mfg, off));
    }
    if (lane == 0) {
        const int wv = tid >> 6;
        wred[wv][0] = a_dx; wred[wv][1] = a_dy; wred[wv][2] = a_sb;
        wred[wv][3] = a_sbf; wred[wv][4] = mfg;
    }
    __syncthreads();
    if (tid == 0) {
        float dx = 0.f, dy = 0.f, sb = 0.f, sbf = 0.f, mf = 0.f;
        for (int i = 0; i < 4; ++i) {
            dx += wred[i][0]; dy += wred[i][1]; sb += wred[i][2];
            sbf += wred[i][3]; mf = fmaxf(mf, wred[i][4]);
        }
        const int sl = bid & 63;
        atomicAdd(&scal64[sl * 4 + 0], (double)dx);
        atomicAdd(&scal64[sl * 4 + 1], (double)dy);
        atomicAdd(&scal64[sl * 4 + 2], (double)sb);
        atomicAdd(&scal64[sl * 4 + 3], (double)sbf);
        atomicMax(&maxfg64[sl], __float_as_uint(mf));
    }
}

__global__ __launch_bounds__(256) void uber_kernel(
    const float* __restrict__ flow,
    const int*   __restrict__ masks,
    const float* __restrict__ images,
    double* __restrict__ moments4,
    double* __restrict__ scal64,
    unsigned* __restrict__ maxfg64)
{
    __shared__ char smem[39936];      // union: moments bins (39936B) | stencil arrays (22960B)
    const int bid = blockIdx.x;       // 3072 = 2048 stencil + 1024 moments, interleaved
    if ((bid % 3) == 2) {
        moments_body(flow, masks, moments4, (float*)smem, bid / 3);
    } else {
        stencil_body(flow, masks, images, scal64, maxfg64, smem,
                     (bid / 3) * 2 + (bid % 3));
    }
}

// ---------------- solve: sum partials, 3x3 normal equations + variance ----------------
__global__ __launch_bounds__(128) void solve_kernel(
    const double* __restrict__ moments4,
    float* __restrict__ params,   // [128][6]
    int* __restrict__ valid,      // [128]
    float* __restrict__ out)
{
    const int i = threadIdx.x;    // (b, seg-1)
    double m[14];
    #pragma unroll
    for (int k = 0; k < 14; ++k) {
        double s = 0.0;
        #pragma unroll
        for (int par = 0; par < 4; ++par) s += moments4[par * 1792 + i * 14 + k];
        m[k] = s;
    }
    const double n = m[0];
    const int vh = (n >= 100.0) ? 1 : 0;
    float p[6] = {0.f, 0.f, 0.f, 0.f, 0.f, 0.f};
    if (vh) {
        double A[3][3] = {{m[3], m[4], m[1]},
                          {m[4], m[5], m[2]},
                          {m[1], m[2], n}};
        double Bm[3][2] = {{m[10], m[12]},
                           {m[11], m[13]},
                           {m[6],  m[7]}};
        for (int k = 0; k < 3; ++k) {
            int piv = k; double mx = fabs(A[k][k]);
            for (int r = k + 1; r < 3; ++r) {
                double a = fabs(A[r][k]);
                if (a > mx) { mx = a; piv = r; }
            }
            if (piv != k) {
                for (int c = 0; c < 3; ++c) { double t = A[k][c]; A[k][c] = A[piv][c]; A[piv][c] = t; }
                for (int c = 0; c < 2; ++c) { double t = Bm[k][c]; Bm[k][c] = Bm[piv][c]; Bm[piv][c] = t; }
            }
            const double inv = 1.0 / A[k][k];
            for (int r = k + 1; r < 3; ++r) {
                const double f = A[r][k] * inv;
                for (int c = k; c < 3; ++c) A[r][c] -= f * A[k][c];
                Bm[r][0] -= f * Bm[k][0];
                Bm[r][1] -= f * Bm[k][1];
            }
        }
        double X[3][2];
        for (int c = 0; c < 2; ++c) {
            X[2][c] = Bm[2][c] / A[2][2];
            X[1][c] = (Bm[1][c] - A[1][2] * X[2][c]) / A[1][1];
            X[0][c] = (Bm[0][c] - A[0][1] * X[1][c] - A[0][2] * X[2][c]) / A[0][0];
        }
        p[0] = (float)X[0][0]; p[1] = (float)X[1][0]; p[2] = (float)X[2][0];
        p[3] = (float)X[0][1]; p[4] = (float)X[1][1]; p[5] = (float)X[2][1];
    }
    valid[i] = vh;
    for (int c = 0; c < 6; ++c) params[i * 6 + c] = p[c];

    const int vv = (n >= 50.0) ? 1 : 0;
    double var = 0.0;
    if (vv) {
        const double ns = (n > 2.0) ? n : 2.0;
        const double var_u = (m[8] - m[6] * m[6] / ns) / (ns - 1.0);
        const double var_v = (m[9] - m[7] * m[7] / ns) / (ns - 1.0);
        var = var_u + var_v;
    }
    __shared__ double svar[128];
    __shared__ int scnt[128];
    svar[i] = var; scnt[i] = vv;
    __syncthreads();
    for (int s = 64; s > 0; s >>= 1) {
        if (i < s) { svar[i] += svar[i + s]; scnt[i] += scnt[i + s]; }
        __syncthreads();
    }
    if (i == 0) out[2] = (float)(svar[0] / (double)(scnt[0] > 1 ? scnt[0] : 1));
}

// ---------------- pass 2: residuals, named-scalar accumulators (r15, validated) ----------------
__global__ __launch_bounds__(256) void pass2_kernel(
    const float* __restrict__ flow,
    const int*   __restrict__ masks,
    const float* __restrict__ params,
    double* __restrict__ res4)        // [4][8][16]
{
    __shared__ float sp[17 * 6];      // row 0 = zeros (background)

    const long long base = (long long)blockIdx.x * 4096;
    const int b      = (int)(base >> 19);
    const int hwbase = (int)(base & (HW - 1));
    const int tid    = threadIdx.x;
    const int lane   = tid & 63;

    if (tid < 6) sp[tid] = 0.f;
    if (tid < 96) sp[6 + tid] = params[b * 96 + tid];
    __syncthreads();

    const float* fu = flow + (long long)b * (2LL * HW);
    const float* fv = fu + HW;
    const int*   mk = masks + (long long)b * HW;

#define DECLR(i) float r_##i = 0.f;
    REP8(DECLR)
#define DECLR2(i) float q_##i = 0.f;
    REP8(DECLR2)

    #pragma unroll
    for (int it = 0; it < 4; ++it) {
        const int i4 = hwbase + it * 1024 + tid * 4;
        const int4   m4 = *(const int4*)&mk[i4];
        const float4 u4 = *(const float4*)&fu[i4];
        const float4 v4 = *(const float4*)&fv[i4];
        const int segs[4] = {m4.x, m4.y, m4.z, m4.w};
        const float us[4] = {u4.x, u4.y, u4.z, u4.w};
        const float vs[4] = {v4.x, v4.y, v4.z, v4.w};
        #pragma unroll
        for (int j = 0; j < 4; ++j) {
            const int seg = segs[j];
            const float* pf = &sp[seg * 6];
            const int hw = i4 + j;
            const float x = (float)(hw & 1023), y = (float)((hw & (HW - 1)) >> 10);
            const float du = us[j] - (x * pf[0] + y * pf[1] + pf[2]);
            const float dv = vs[j] - (x * pf[3] + y * pf[4] + pf[5]);
            const float r = sqrtf(du * du + dv * dv);
            const int sr = seg - 1;
#define STEPR(i) r_##i += (sr == i) ? r : 0.f;
            REP8(STEPR)
#define STEPR2(i) q_##i += (sr == 8 + i) ? r : 0.f;
            REP8(STEPR2)
        }
    }

    const int par = blockIdx.x & 3;
    double* rb = &res4[par * 128 + b * 16];
#define FINR(i) { const float s = wave_sum(r_##i); \
    if (lane == 0) atomicAdd(rb + i, (double)s); }
    REP8(FINR)
#define FINR2(i) { const float s = wave_sum(q_##i); \
    if (lane == 0) atomicAdd(rb + 8 + i, (double)s); }
    REP8(FINR2)
}

// ---------------- finalize: homog, sharp, smooth ----------------
__global__ __launch_bounds__(128) void final_kernel(
    const double* __restrict__ moments4,
    const double* __restrict__ res4,
    const int*    __restrict__ valid,
    const double* __restrict__ scal64,
    const unsigned* __restrict__ maxfg64,
    float* __restrict__ out)
{
    const int i = threadIdx.x;
    double n = 0.0, rs = 0.0;
    #pragma unroll
    for (int par = 0; par < 4; ++par) {
        n  += moments4[par * 1792 + i * 14];
        rs += res4[par * 128 + i];
    }
    const int vh = valid[i];
    const double rm = vh ? rs / (n > 1.0 ? n : 1.0) : 0.0;
    __shared__ double sr[128];
    __shared__ int sc[128];
    sr[i] = rm; sc[i] = vh;
    __syncthreads();
    for (int s = 64; s > 0; s >>= 1) {
        if (i < s) { sr[i] += sr[i + s]; sc[i] += sc[i + s]; }
        __syncthreads();
    }
    if (i == 0) {
        out[0] = (float)(sr[0] / (double)(sc[0] > 1 ? sc[0] : 1));
        double dx = 0.0, dy = 0.0, sb = 0.0, sbf = 0.0;
        float mf = 0.f;
        for (int k = 0; k < 64; ++k) {
            dx += scal64[k * 4 + 0]; dy += scal64[k * 4 + 1];
            sb += scal64[k * 4 + 2]; sbf += scal64[k * 4 + 3];
            mf = fmaxf(mf, __uint_as_float(maxfg64[k]));
        }
        const double maxfg = (double)mf;
        const double maxb = (sb > 0.0) ? 1.0 : 0.0;
        out[1] = (float)((sb - sbf / (maxfg + 1e-6)) / (maxb + 1e-6) / (double)NPIX);
        const double smooth = dx / (double)(2LL * BB * HH * (WW - 1)) +
                              dy / (double)(2LL * BB * (HH - 1) * WW);
        out[3] = (float)smooth;
    }
}

extern "C" void kernel_launch(void* const* d_in, const int* in_sizes, int n_in,
                              void* d_out, int out_size, void* d_ws, size_t ws_size,
                              hipStream_t stream)
{
    const float* flow   = (const float*)d_in[0];
    const int*   masks  = (const int*)d_in[1];
    const float* images = (const float*)d_in[2];
    float* out = (float*)d_out;

    char* ws = (char*)d_ws;
    double*   moments4 = (double*)(ws);             // 0     .. 57344
    double*   res4     = (double*)(ws + 57344);     // 57344 .. 61440
    double*   scal64   = (double*)(ws + 61440);     // 61440 .. 63488
    unsigned* maxfg64  = (unsigned*)(ws + 63488);   // 63488 .. 63744
    float*    params   = (float*)(ws + 63744);      // 63744 .. 66816
    int*      valid    = (int*)(ws + 66816);        // 66816 .. 67328

    hipMemsetAsync(d_ws, 0, 67584, stream);

    uber_kernel<<<dim3(3072), dim3(256), 0, stream>>>(
        flow, masks, images, moments4, scal64, maxfg64);
    solve_kernel<<<dim3(1), dim3(128), 0, stream>>>(moments4, params, valid, out);
    pass2_kernel<<<dim3(NPIX / 4096), dim3(256), 0, stream>>>(
        flow, masks, params, res4);
    final_kernel<<<dim3(1), dim3(128), 0, stream>>>(
        moments4, res4, valid, scal64, maxfg64, out);
}